// Round 6
// baseline (654.883 us; speedup 1.0000x reference)
//
#include <hip/hip_runtime.h>
#include <cstdint>
#include <cstddef>

// ---------------------------------------------------------------------------
// KAN encode: x(4096,1024) -> KANLinear(1024->2048) -> KANLinear(2048->1024)
//             -> ReLU -> Dense(1024->512)+bias
// bf16 MFMA GEMMs over augmented K (9 channels per input feature).
// R6: gemm_big was LDS-BW-bound (144 KB/CU/K32-step vs 128 B/cyc).
//     - A fragments now loaded global->VGPR directly (prefetched one
//       half-step ahead); A no longer staged through LDS.
//     - W LDS layout XOR-swizzled (source-side, since global_load_lds pins
//       dst = base + lane*16) to kill frag-read bank conflicts.
//     LDS/step: 144 KB -> 80 KB. Keeps XCD m-slab swizzle + W dbuf.
// ---------------------------------------------------------------------------

typedef __bf16 bf16x8 __attribute__((ext_vector_type(8)));
typedef float floatx4 __attribute__((ext_vector_type(4)));

#define BATCH 4096
#define DIN   1024
#define H0N   2048
#define H1N   1024
#define LOUT  512

// Workspace layout (bytes). Total = 227,540,992.
#define OFF_A0  ((size_t)0)           // bf16 4096*9216  = 75,497,472
#define OFF_W0  ((size_t)75497472)    // bf16 2048*9216  = 37,748,736
#define OFF_A1  ((size_t)0)           // bf16 4096*18432 = 150,994,944 (overlays A0+W0)
#define OFF_P0  ((size_t)150994944)   // f32 2*4096*2048 = 67,108,864
#define OFF_W1  ((size_t)218103808)   // bf16 1024*18432 = 37,748,736
#define OFF_P1  ((size_t)150994944)   // f32 4*4096*1024 = 67,108,864 (overlays P0)
#define OFF_H1R ((size_t)218103808)   // bf16 4096*1024  =  8,388,608 (overlays W1)
#define OFF_DW  ((size_t)226492416)   // bf16 512*1024   =  1,048,576

// --------------------------- spline bases ----------------------------------
__device__ __forceinline__ void bspline8(float x, float* out) {
    float b[11];
#pragma unroll
    for (int j = 0; j < 11; ++j) {
        float t0 = (j - 3) * 0.4f - 1.0f;
        float t1 = (j - 2) * 0.4f - 1.0f;
        b[j] = (x >= t0 && x < t1) ? 1.0f : 0.0f;
    }
#pragma unroll
    for (int k = 1; k <= 3; ++k) {
#pragma unroll
        for (int j = 0; j + k < 11; ++j) {
            float tj   = (j - 3) * 0.4f - 1.0f;
            float tj1  = (j - 2) * 0.4f - 1.0f;
            float tjk  = (j + k - 3) * 0.4f - 1.0f;
            float tjk1 = (j + k - 2) * 0.4f - 1.0f;
            float left  = (x - tj)   * (1.0f / (tjk - tj));
            float right = (tjk1 - x) * (1.0f / (tjk1 - tj1));
            b[j] = left * b[j] + right * b[j + 1];
        }
    }
#pragma unroll
    for (int j = 0; j < 8; ++j) out[j] = b[j];
}

// Store 256 threads * 9 bf16 via LDS as 288 coalesced 16B chunks.
__device__ __forceinline__ void coalesced_store9(__bf16* block_dst, const __bf16* vals) {
    __shared__ __bf16 sbuf[256 * 9];
    __bf16* p = &sbuf[threadIdx.x * 9];
#pragma unroll
    for (int j = 0; j < 9; ++j) p[j] = vals[j];
    __syncthreads();
    const uint4* src = (const uint4*)sbuf;
    uint4* dst = (uint4*)block_dst;
    dst[threadIdx.x] = src[threadIdx.x];
    if (threadIdx.x < 32) dst[256 + threadIdx.x] = src[256 + threadIdx.x];
}

__device__ __forceinline__ void act9(float v, __bf16* r) {
    float s = v / (1.0f + __expf(-v));
    float bb[8];
    bspline8(v, bb);
    r[0] = (__bf16)s;
#pragma unroll
    for (int j = 0; j < 8; ++j) r[1 + j] = (__bf16)bb[j];
}

__global__ void kan_act(const float* __restrict__ in, __bf16* __restrict__ out) {
    int base = blockIdx.x * 256;
    float v = in[base + threadIdx.x];
    __bf16 r[9];
    act9(v, r);
    coalesced_store9(out + (size_t)base * 9, r);
}

__global__ void kan_act_sum2(const float* __restrict__ pa, const float* __restrict__ pb,
                             __bf16* __restrict__ out) {
    int base = blockIdx.x * 256;
    int idx = base + threadIdx.x;
    float v = pa[idx] + pb[idx];
    __bf16 r[9];
    act9(v, r);
    coalesced_store9(out + (size_t)base * 9, r);
}

__global__ void relu_sum4(const float* __restrict__ p, size_t stride,
                          __bf16* __restrict__ out, int total4) {
    int idx = blockIdx.x * 256 + threadIdx.x;
    if (idx >= total4) return;
    const float4* p0 = (const float4*)p;
    const float4* p1 = (const float4*)(p + stride);
    const float4* p2 = (const float4*)(p + 2 * stride);
    const float4* p3 = (const float4*)(p + 3 * stride);
    float4 a = p0[idx], b = p1[idx], c = p2[idx], d = p3[idx];
    __bf16 r[4];
    r[0] = (__bf16)fmaxf(a.x + b.x + c.x + d.x, 0.0f);
    r[1] = (__bf16)fmaxf(a.y + b.y + c.y + d.y, 0.0f);
    r[2] = (__bf16)fmaxf(a.z + b.z + c.z + d.z, 0.0f);
    r[3] = (__bf16)fmaxf(a.w + b.w + c.w + d.w, 0.0f);
    *(uint2*)&out[(size_t)idx * 4] = *(uint2*)r;
}

__global__ void kan_wprep(const float* __restrict__ bw, const float* __restrict__ sw,
                          const float* __restrict__ ss, __bf16* __restrict__ out) {
    int base = blockIdx.x * 256;
    int idx = base + threadIdx.x;
    float b  = bw[idx];
    float sc = ss[idx];
    const float4* sv = (const float4*)(sw + (size_t)idx * 8);
    float4 a = sv[0], c = sv[1];
    __bf16 r[9];
    r[0] = (__bf16)b;
    r[1] = (__bf16)(a.x * sc); r[2] = (__bf16)(a.y * sc);
    r[3] = (__bf16)(a.z * sc); r[4] = (__bf16)(a.w * sc);
    r[5] = (__bf16)(c.x * sc); r[6] = (__bf16)(c.y * sc);
    r[7] = (__bf16)(c.z * sc); r[8] = (__bf16)(c.w * sc);
    coalesced_store9(out + (size_t)base * 9, r);
}

__global__ void f2bf(const float* __restrict__ in, __bf16* __restrict__ out,
                     int total) {
    int idx = blockIdx.x * 256 + threadIdx.x;
    if (idx < total) out[idx] = (__bf16)in[idx];
}

// --------------------------- staging helper --------------------------------
__device__ __forceinline__ void gload_lds16(const void* g, void* l) {
    __builtin_amdgcn_global_load_lds(
        (const __attribute__((address_space(1))) uint32_t*)g,
        (__attribute__((address_space(3))) uint32_t*)l, 16, 0, 0);
}

// ----------------- big-tile MFMA GEMM: 256x128, wave 64x128 ----------------
// C(M,N) = A(M,K) @ W(N,K)^T, bf16 in, fp32 out (split-K partial per z).
// A fragments: direct global->VGPR (per-lane 16B, prefetched one half-step).
// W: dbuf LDS via global_load_lds, XOR-swizzled chunk placement.
// XCD swizzle: each XCD owns a contiguous m-slab. gridDim.y % 8 == 0.
__global__ __launch_bounds__(256, 2) void gemm_big(
    const __bf16* __restrict__ A, const __bf16* __restrict__ W,
    float* __restrict__ Cout, int M, int N, int K, int Ks) {
    constexpr int BK = 32;                    // 64 B LDS rows (4 x 16B chunks)
    __shared__ __bf16 Ws[2][128 * BK];        // 2 x 8 KB

    const int tid  = threadIdx.x;
    const int lane = tid & 63;
    const int wave = tid >> 6;

    // XCD-aware swizzle (round-robin dispatch: id&7 = XCD)
    const int id    = (blockIdx.z * gridDim.y + blockIdx.y) * gridDim.x + blockIdx.x;
    const int mslab = gridDim.y >> 3;
    const int xcd   = id & 7;
    const int local = id >> 3;
    const int m_off = local % mslab;
    const int rest  = local / mslab;
    const int ntile = rest % gridDim.x;
    const int zt    = rest / gridDim.x;
    const int bm    = (xcd * mslab + m_off) * 256;
    const int bn    = ntile * 128;
    const int kbase = zt * Ks;

    const int wm = wave * 64;
    const int lr = lane & 15;
    const int kq = lane >> 4;       // k-chunk index 0..3
    const int ks = kq * 8;          // k elem offset

    floatx4 acc[4][8] = {};

    // Stage W tile (128 x BK) into buf, XOR-swizzled: LDS slot (row r, pos p)
    // holds global chunk q = p ^ s(r), s(r) = (r ^ (r>>2)) & 3.
    auto stageW = [&](int buf, int kpos) {
#pragma unroll
        for (int i = 0; i < 2; ++i) {
            int c = i * 256 + tid;           // chunk slot 0..511
            int r = c >> 2;                  // W row
            int p = c & 3;                   // slot position in row
            int q = p ^ ((r ^ (r >> 2)) & 3);
            gload_lds16(&W[(size_t)(bn + r) * K + kbase + kpos + q * 8],
                        &Ws[buf][(size_t)(i * 256 + wave * 64) * 8]);
        }
    };

    // A fragments direct from global: lane reads 16B of row (wm + t*16 + lr).
    auto aload = [&](int kpos, bf16x8* af) {
#pragma unroll
        for (int t = 0; t < 4; ++t)
            af[t] = *(const bf16x8*)&A[(size_t)(bm + wm + t * 16 + lr) * K +
                                       kbase + kpos + ks];
    };

    auto compute = [&](int buf, const bf16x8* af) {
        bf16x8 wf[8];
#pragma unroll
        for (int t = 0; t < 8; ++t) {
            int r = t * 16 + lr;
            int p = kq ^ ((r ^ (r >> 2)) & 3);   // swizzled chunk position
            wf[t] = *(const bf16x8*)&Ws[buf][r * BK + p * 8];
        }
#pragma unroll
        for (int mt = 0; mt < 4; ++mt)
#pragma unroll
            for (int nt = 0; nt < 8; ++nt)
                acc[mt][nt] = __builtin_amdgcn_mfma_f32_16x16x32_bf16(
                    af[mt], wf[nt], acc[mt][nt], 0, 0, 0);
    };

    bf16x8 afA[4], afB[4];
    stageW(0, 0);
    aload(0, afA);
    for (int k0 = 0; k0 < Ks; k0 += 2 * BK) {
        __syncthreads();                        // Ws[0] for k0 ready
        if (k0 + BK < Ks) stageW(1, k0 + BK);
        aload(k0 + BK, afB);                    // prefetch A for next half
        compute(0, afA);
        __syncthreads();                        // Ws[1] ready
        if (k0 + 2 * BK < Ks) {
            stageW(0, k0 + 2 * BK);
            aload(k0 + 2 * BK, afA);
        }
        compute(1, afB);
    }

    // C/D layout: col = lane&15, row = (lane>>4)*4 + reg
    float* Cz = Cout + (size_t)zt * M * N;
    const int col = lane & 15;
    const int rquad = (lane >> 4) * 4;
#pragma unroll
    for (int mt = 0; mt < 4; ++mt) {
#pragma unroll
        for (int nt = 0; nt < 8; ++nt) {
            int n = bn + nt * 16 + col;
#pragma unroll
            for (int rg = 0; rg < 4; ++rg) {
                int m = bm + wm + mt * 16 + rquad + rg;
                Cz[(size_t)m * N + n] = acc[mt][nt][rg];
            }
        }
    }
}

// ----------------- 128x128 MFMA GEMM (dense epilogue) ----------------------
__global__ __launch_bounds__(256) void gemm_dense(
    const __bf16* __restrict__ A, const __bf16* __restrict__ W,
    float* __restrict__ Cout, const float* __restrict__ bias,
    int M, int N, int K) {
    constexpr int BK = 32;
    __shared__ __bf16 As[2][128 * BK];
    __shared__ __bf16 Ws[2][128 * BK];

    const int tid  = threadIdx.x;
    const int lane = tid & 63;
    const int wave = tid >> 6;

    const int id    = blockIdx.y * gridDim.x + blockIdx.x;
    const int mslab = gridDim.y >> 3;
    const int xcd   = id & 7;
    const int local = id >> 3;
    const int m_off = local % mslab;
    const int ntile = local / mslab;
    const int bm    = (xcd * mslab + m_off) * 128;
    const int bn    = ntile * 128;

    const int wm = (wave >> 1) * 64;
    const int wn = (wave & 1) * 64;
    const int lr = lane & 15;
    const int ks = (lane >> 4) * 8;

    floatx4 acc[4][4] = {};

    auto stage = [&](int buf, int kpos) {
#pragma unroll
        for (int i = 0; i < 2; ++i) {
            int c = i * 256 + tid;
            int r = c >> 2;
            int s = (c & 3) * 8;
            gload_lds16(&A[(size_t)(bm + r) * K + kpos + s],
                        &As[buf][(size_t)(i * 256 + wave * 64) * 8]);
            gload_lds16(&W[(size_t)(bn + r) * K + kpos + s],
                        &Ws[buf][(size_t)(i * 256 + wave * 64) * 8]);
        }
    };

    auto compute = [&](int buf) {
        bf16x8 af[4], wf[4];
#pragma unroll
        for (int t = 0; t < 4; ++t) {
            af[t] = *(const bf16x8*)&As[buf][(wm + t * 16 + lr) * BK + ks];
            wf[t] = *(const bf16x8*)&Ws[buf][(wn + t * 16 + lr) * BK + ks];
        }
#pragma unroll
        for (int mt = 0; mt < 4; ++mt)
#pragma unroll
            for (int nt = 0; nt < 4; ++nt)
                acc[mt][nt] = __builtin_amdgcn_mfma_f32_16x16x32_bf16(
                    af[mt], wf[nt], acc[mt][nt], 0, 0, 0);
    };

    stage(0, 0);
    for (int k0 = 0; k0 < K; k0 += 2 * BK) {
        __syncthreads();
        if (k0 + BK < K) stage(1, k0 + BK);
        compute(0);
        __syncthreads();
        if (k0 + 2 * BK < K) stage(0, k0 + 2 * BK);
        compute(1);
    }

    const int col = lane & 15;
    const int rquad = (lane >> 4) * 4;
#pragma unroll
    for (int mt = 0; mt < 4; ++mt) {
#pragma unroll
        for (int nt = 0; nt < 4; ++nt) {
            int n = bn + wn + nt * 16 + col;
#pragma unroll
            for (int rg = 0; rg < 4; ++rg) {
                int m = bm + wm + mt * 16 + rquad + rg;
                Cout[(size_t)m * N + n] = acc[mt][nt][rg] + bias[n];
            }
        }
    }
}

// ---------------------------------------------------------------------------
extern "C" void kernel_launch(void* const* d_in, const int* in_sizes, int n_in,
                              void* d_out, int out_size, void* d_ws, size_t ws_size,
                              hipStream_t stream) {
    const float* x   = (const float*)d_in[0];
    const float* bw0 = (const float*)d_in[1];
    const float* sw0 = (const float*)d_in[2];
    const float* ss0 = (const float*)d_in[3];
    const float* bw1 = (const float*)d_in[4];
    const float* sw1 = (const float*)d_in[5];
    const float* ss1 = (const float*)d_in[6];
    const float* dw  = (const float*)d_in[7];
    const float* db  = (const float*)d_in[8];
    float* out = (float*)d_out;

    char* ws = (char*)d_ws;
    __bf16* A0  = (__bf16*)(ws + OFF_A0);
    __bf16* W0  = (__bf16*)(ws + OFF_W0);
    __bf16* A1  = (__bf16*)(ws + OFF_A1);
    float*  P0  = (float*)(ws + OFF_P0);
    __bf16* W1  = (__bf16*)(ws + OFF_W1);
    float*  P1  = (float*)(ws + OFF_P1);
    __bf16* h1r = (__bf16*)(ws + OFF_H1R);
    __bf16* dwb = (__bf16*)(ws + OFF_DW);

    // Layer 0: K = 9216, splitK=2 -> grid 16x16x2 = 512 blocks (2/CU)
    kan_wprep<<<(H0N * DIN) / 256, 256, 0, stream>>>(bw0, sw0, ss0, W0);
    kan_act<<<(BATCH * DIN) / 256, 256, 0, stream>>>(x, A0);
    gemm_big<<<dim3(H0N / 128, BATCH / 256, 2), 256, 0, stream>>>(
        A0, W0, P0, BATCH, H0N, DIN * 9, DIN * 9 / 2);

    // Layer 1: K = 18432, splitK=4 -> grid 8x16x4 = 512 blocks (2/CU)
    kan_wprep<<<(H1N * H0N) / 256, 256, 0, stream>>>(bw1, sw1, ss1, W1);
    kan_act_sum2<<<(BATCH * H0N) / 256, 256, 0, stream>>>(
        P0, P0 + (size_t)BATCH * H0N, A1);
    gemm_big<<<dim3(H1N / 128, BATCH / 256, 4), 256, 0, stream>>>(
        A1, W1, P1, BATCH, H1N, H0N * 9, H0N * 9 / 4);

    // relu(sum of 4 partials) -> bf16
    relu_sum4<<<(BATCH * H1N / 4) / 256, 256, 0, stream>>>(
        P1, (size_t)BATCH * H1N, h1r, BATCH * H1N / 4);

    // Dense: out = h1r @ dw^T + db  (K = 1024)
    f2bf<<<(LOUT * H1N) / 256, 256, 0, stream>>>(dw, dwb, LOUT * H1N);
    gemm_dense<<<dim3(LOUT / 128, BATCH / 128), 256, 0, stream>>>(
        h1r, dwb, out, db, BATCH, LOUT, H1N);
}

// Round 7
// 617.945 us; speedup vs baseline: 1.0598x; 1.0598x over previous
//
#include <hip/hip_runtime.h>
#include <cstdint>
#include <cstddef>

// ---------------------------------------------------------------------------
// KAN encode: x(4096,1024) -> KANLinear(1024->2048) -> KANLinear(2048->1024)
//             -> ReLU -> Dense(1024->512)+bias
// bf16 MFMA GEMMs over augmented K (9 channels per input feature).
// R7: revert to R5 structure (A staged in LDS — R6's global A-frags moved
//     traffic to the narrower L1 path and regressed). Proper XOR bank
//     swizzle s(r)=(r>>1)&3 on BOTH A and W tiles (source-side address
//     permutation; global_load_lds pins dst = base + lane*16). Frag reads
//     become 2-way bank aliased = free (m136).
// ---------------------------------------------------------------------------

typedef __bf16 bf16x8 __attribute__((ext_vector_type(8)));
typedef float floatx4 __attribute__((ext_vector_type(4)));

#define BATCH 4096
#define DIN   1024
#define H0N   2048
#define H1N   1024
#define LOUT  512

// Workspace layout (bytes). Total = 227,540,992.
#define OFF_A0  ((size_t)0)           // bf16 4096*9216  = 75,497,472
#define OFF_W0  ((size_t)75497472)    // bf16 2048*9216  = 37,748,736
#define OFF_A1  ((size_t)0)           // bf16 4096*18432 = 150,994,944 (overlays A0+W0)
#define OFF_P0  ((size_t)150994944)   // f32 2*4096*2048 = 67,108,864
#define OFF_W1  ((size_t)218103808)   // bf16 1024*18432 = 37,748,736
#define OFF_P1  ((size_t)150994944)   // f32 4*4096*1024 = 67,108,864 (overlays P0)
#define OFF_H1R ((size_t)218103808)   // bf16 4096*1024  =  8,388,608 (overlays W1)
#define OFF_DW  ((size_t)226492416)   // bf16 512*1024   =  1,048,576

// --------------------------- spline bases ----------------------------------
__device__ __forceinline__ void bspline8(float x, float* out) {
    float b[11];
#pragma unroll
    for (int j = 0; j < 11; ++j) {
        float t0 = (j - 3) * 0.4f - 1.0f;
        float t1 = (j - 2) * 0.4f - 1.0f;
        b[j] = (x >= t0 && x < t1) ? 1.0f : 0.0f;
    }
#pragma unroll
    for (int k = 1; k <= 3; ++k) {
#pragma unroll
        for (int j = 0; j + k < 11; ++j) {
            float tj   = (j - 3) * 0.4f - 1.0f;
            float tj1  = (j - 2) * 0.4f - 1.0f;
            float tjk  = (j + k - 3) * 0.4f - 1.0f;
            float tjk1 = (j + k - 2) * 0.4f - 1.0f;
            float left  = (x - tj)   * (1.0f / (tjk - tj));
            float right = (tjk1 - x) * (1.0f / (tjk1 - tj1));
            b[j] = left * b[j] + right * b[j + 1];
        }
    }
#pragma unroll
    for (int j = 0; j < 8; ++j) out[j] = b[j];
}

// Store 256 threads * 9 bf16 via LDS as 288 coalesced 16B chunks.
__device__ __forceinline__ void coalesced_store9(__bf16* block_dst, const __bf16* vals) {
    __shared__ __bf16 sbuf[256 * 9];
    __bf16* p = &sbuf[threadIdx.x * 9];
#pragma unroll
    for (int j = 0; j < 9; ++j) p[j] = vals[j];
    __syncthreads();
    const uint4* src = (const uint4*)sbuf;
    uint4* dst = (uint4*)block_dst;
    dst[threadIdx.x] = src[threadIdx.x];
    if (threadIdx.x < 32) dst[256 + threadIdx.x] = src[256 + threadIdx.x];
}

__device__ __forceinline__ void act9(float v, __bf16* r) {
    float s = v / (1.0f + __expf(-v));
    float bb[8];
    bspline8(v, bb);
    r[0] = (__bf16)s;
#pragma unroll
    for (int j = 0; j < 8; ++j) r[1 + j] = (__bf16)bb[j];
}

__global__ void kan_act(const float* __restrict__ in, __bf16* __restrict__ out) {
    int base = blockIdx.x * 256;
    float v = in[base + threadIdx.x];
    __bf16 r[9];
    act9(v, r);
    coalesced_store9(out + (size_t)base * 9, r);
}

__global__ void kan_act_sum2(const float* __restrict__ pa, const float* __restrict__ pb,
                             __bf16* __restrict__ out) {
    int base = blockIdx.x * 256;
    int idx = base + threadIdx.x;
    float v = pa[idx] + pb[idx];
    __bf16 r[9];
    act9(v, r);
    coalesced_store9(out + (size_t)base * 9, r);
}

__global__ void relu_sum4(const float* __restrict__ p, size_t stride,
                          __bf16* __restrict__ out, int total4) {
    int idx = blockIdx.x * 256 + threadIdx.x;
    if (idx >= total4) return;
    const float4* p0 = (const float4*)p;
    const float4* p1 = (const float4*)(p + stride);
    const float4* p2 = (const float4*)(p + 2 * stride);
    const float4* p3 = (const float4*)(p + 3 * stride);
    float4 a = p0[idx], b = p1[idx], c = p2[idx], d = p3[idx];
    __bf16 r[4];
    r[0] = (__bf16)fmaxf(a.x + b.x + c.x + d.x, 0.0f);
    r[1] = (__bf16)fmaxf(a.y + b.y + c.y + d.y, 0.0f);
    r[2] = (__bf16)fmaxf(a.z + b.z + c.z + d.z, 0.0f);
    r[3] = (__bf16)fmaxf(a.w + b.w + c.w + d.w, 0.0f);
    *(uint2*)&out[(size_t)idx * 4] = *(uint2*)r;
}

__global__ void kan_wprep(const float* __restrict__ bw, const float* __restrict__ sw,
                          const float* __restrict__ ss, __bf16* __restrict__ out) {
    int base = blockIdx.x * 256;
    int idx = base + threadIdx.x;
    float b  = bw[idx];
    float sc = ss[idx];
    const float4* sv = (const float4*)(sw + (size_t)idx * 8);
    float4 a = sv[0], c = sv[1];
    __bf16 r[9];
    r[0] = (__bf16)b;
    r[1] = (__bf16)(a.x * sc); r[2] = (__bf16)(a.y * sc);
    r[3] = (__bf16)(a.z * sc); r[4] = (__bf16)(a.w * sc);
    r[5] = (__bf16)(c.x * sc); r[6] = (__bf16)(c.y * sc);
    r[7] = (__bf16)(c.z * sc); r[8] = (__bf16)(c.w * sc);
    coalesced_store9(out + (size_t)base * 9, r);
}

__global__ void f2bf(const float* __restrict__ in, __bf16* __restrict__ out,
                     int total) {
    int idx = blockIdx.x * 256 + threadIdx.x;
    if (idx < total) out[idx] = (__bf16)in[idx];
}

// --------------------------- staging helper --------------------------------
__device__ __forceinline__ void gload_lds16(const void* g, void* l) {
    __builtin_amdgcn_global_load_lds(
        (const __attribute__((address_space(1))) uint32_t*)g,
        (__attribute__((address_space(3))) uint32_t*)l, 16, 0, 0);
}

// Bank swizzle: LDS slot (row r, pos p) holds global chunk q = p ^ ((r>>1)&3).
// For frag reads (rows base+lr, lr=0..15) the swizzled chunk position is
// kq ^ ((lr>>1)&3): the 16 lanes of a k-quad then cover all 8 (row-parity,
// chunk) bank groups exactly twice -> 2-way aliasing = free.

// ----------------- big-tile MFMA GEMM: 256x128, wave 64x128 ----------------
// C(M,N) = A(M,K) @ W(N,K)^T, bf16 in, fp32 out (split-K partial per z).
// A and W staged in dbuf LDS via global_load_lds, XOR bank swizzle.
// XCD swizzle: each XCD owns a contiguous m-slab. gridDim.y % 8 == 0.
__global__ __launch_bounds__(256, 2) void gemm_big(
    const __bf16* __restrict__ A, const __bf16* __restrict__ W,
    float* __restrict__ Cout, int M, int N, int K, int Ks) {
    constexpr int BK = 32;                    // 64 B LDS rows (4 x 16B chunks)
    __shared__ __bf16 As[2][256 * BK];        // 2 x 16 KB
    __shared__ __bf16 Ws[2][128 * BK];        // 2 x 8 KB

    const int tid  = threadIdx.x;
    const int lane = tid & 63;
    const int wave = tid >> 6;

    // XCD-aware swizzle (round-robin dispatch: id&7 = XCD)
    const int id    = (blockIdx.z * gridDim.y + blockIdx.y) * gridDim.x + blockIdx.x;
    const int mslab = gridDim.y >> 3;
    const int xcd   = id & 7;
    const int local = id >> 3;
    const int m_off = local % mslab;
    const int rest  = local / mslab;
    const int ntile = rest % gridDim.x;
    const int zt    = rest / gridDim.x;
    const int bm    = (xcd * mslab + m_off) * 256;
    const int bn    = ntile * 128;
    const int kbase = zt * Ks;

    const int wm = wave * 64;
    const int lr = lane & 15;
    const int kq = lane >> 4;                      // k-chunk 0..3
    const int kssw = (kq ^ ((lr >> 1) & 3)) * 8;   // swizzled frag chunk offset

    floatx4 acc[4][8] = {};

    auto stage = [&](int buf, int kpos) {
#pragma unroll
        for (int i = 0; i < 4; ++i) {          // A: 1024 chunks of 16 B
            int c = i * 256 + tid;
            int r = c >> 2;
            int q = (c & 3) ^ ((r >> 1) & 3);  // swizzled source chunk
            gload_lds16(&A[(size_t)(bm + r) * K + kbase + kpos + q * 8],
                        &As[buf][(size_t)(i * 256 + wave * 64) * 8]);
        }
#pragma unroll
        for (int i = 0; i < 2; ++i) {          // W: 512 chunks
            int c = i * 256 + tid;
            int r = c >> 2;
            int q = (c & 3) ^ ((r >> 1) & 3);
            gload_lds16(&W[(size_t)(bn + r) * K + kbase + kpos + q * 8],
                        &Ws[buf][(size_t)(i * 256 + wave * 64) * 8]);
        }
    };

    auto compute = [&](int buf) {
        bf16x8 af[4], wf[8];
#pragma unroll
        for (int t = 0; t < 4; ++t)
            af[t] = *(const bf16x8*)&As[buf][(wm + t * 16 + lr) * BK + kssw];
#pragma unroll
        for (int t = 0; t < 8; ++t)
            wf[t] = *(const bf16x8*)&Ws[buf][(t * 16 + lr) * BK + kssw];
#pragma unroll
        for (int mt = 0; mt < 4; ++mt)
#pragma unroll
            for (int nt = 0; nt < 8; ++nt)
                acc[mt][nt] = __builtin_amdgcn_mfma_f32_16x16x32_bf16(
                    af[mt], wf[nt], acc[mt][nt], 0, 0, 0);
    };

    stage(0, 0);
    for (int k0 = 0; k0 < Ks; k0 += 2 * BK) {
        __syncthreads();
        if (k0 + BK < Ks) stage(1, k0 + BK);
        compute(0);
        __syncthreads();
        if (k0 + 2 * BK < Ks) stage(0, k0 + 2 * BK);
        compute(1);
    }

    // C/D layout: col = lane&15, row = (lane>>4)*4 + reg
    float* Cz = Cout + (size_t)zt * M * N;
    const int col = lane & 15;
    const int rquad = (lane >> 4) * 4;
#pragma unroll
    for (int mt = 0; mt < 4; ++mt) {
#pragma unroll
        for (int nt = 0; nt < 8; ++nt) {
            int n = bn + nt * 16 + col;
#pragma unroll
            for (int rg = 0; rg < 4; ++rg) {
                int m = bm + wm + mt * 16 + rquad + rg;
                Cz[(size_t)m * N + n] = acc[mt][nt][rg];
            }
        }
    }
}

// ----------------- 128x128 MFMA GEMM (dense epilogue) ----------------------
__global__ __launch_bounds__(256) void gemm_dense(
    const __bf16* __restrict__ A, const __bf16* __restrict__ W,
    float* __restrict__ Cout, const float* __restrict__ bias,
    int M, int N, int K) {
    constexpr int BK = 32;
    __shared__ __bf16 As[2][128 * BK];
    __shared__ __bf16 Ws[2][128 * BK];

    const int tid  = threadIdx.x;
    const int lane = tid & 63;
    const int wave = tid >> 6;

    const int id    = blockIdx.y * gridDim.x + blockIdx.x;
    const int mslab = gridDim.y >> 3;
    const int xcd   = id & 7;
    const int local = id >> 3;
    const int m_off = local % mslab;
    const int ntile = local / mslab;
    const int bm    = (xcd * mslab + m_off) * 128;
    const int bn    = ntile * 128;

    const int wm = (wave >> 1) * 64;
    const int wn = (wave & 1) * 64;
    const int lr = lane & 15;
    const int kq = lane >> 4;
    const int kssw = (kq ^ ((lr >> 1) & 3)) * 8;

    floatx4 acc[4][4] = {};

    auto stage = [&](int buf, int kpos) {
#pragma unroll
        for (int i = 0; i < 2; ++i) {
            int c = i * 256 + tid;
            int r = c >> 2;
            int q = (c & 3) ^ ((r >> 1) & 3);
            gload_lds16(&A[(size_t)(bm + r) * K + kpos + q * 8],
                        &As[buf][(size_t)(i * 256 + wave * 64) * 8]);
            gload_lds16(&W[(size_t)(bn + r) * K + kpos + q * 8],
                        &Ws[buf][(size_t)(i * 256 + wave * 64) * 8]);
        }
    };

    auto compute = [&](int buf) {
        bf16x8 af[4], wf[4];
#pragma unroll
        for (int t = 0; t < 4; ++t) {
            af[t] = *(const bf16x8*)&As[buf][(wm + t * 16 + lr) * BK + kssw];
            wf[t] = *(const bf16x8*)&Ws[buf][(wn + t * 16 + lr) * BK + kssw];
        }
#pragma unroll
        for (int mt = 0; mt < 4; ++mt)
#pragma unroll
            for (int nt = 0; nt < 4; ++nt)
                acc[mt][nt] = __builtin_amdgcn_mfma_f32_16x16x32_bf16(
                    af[mt], wf[nt], acc[mt][nt], 0, 0, 0);
    };

    stage(0, 0);
    for (int k0 = 0; k0 < K; k0 += 2 * BK) {
        __syncthreads();
        if (k0 + BK < K) stage(1, k0 + BK);
        compute(0);
        __syncthreads();
        if (k0 + 2 * BK < K) stage(0, k0 + 2 * BK);
        compute(1);
    }

    const int col = lane & 15;
    const int rquad = (lane >> 4) * 4;
#pragma unroll
    for (int mt = 0; mt < 4; ++mt) {
#pragma unroll
        for (int nt = 0; nt < 4; ++nt) {
            int n = bn + wn + nt * 16 + col;
#pragma unroll
            for (int rg = 0; rg < 4; ++rg) {
                int m = bm + wm + mt * 16 + rquad + rg;
                Cout[(size_t)m * N + n] = acc[mt][nt][rg] + bias[n];
            }
        }
    }
}

// ---------------------------------------------------------------------------
extern "C" void kernel_launch(void* const* d_in, const int* in_sizes, int n_in,
                              void* d_out, int out_size, void* d_ws, size_t ws_size,
                              hipStream_t stream) {
    const float* x   = (const float*)d_in[0];
    const float* bw0 = (const float*)d_in[1];
    const float* sw0 = (const float*)d_in[2];
    const float* ss0 = (const float*)d_in[3];
    const float* bw1 = (const float*)d_in[4];
    const float* sw1 = (const float*)d_in[5];
    const float* ss1 = (const float*)d_in[6];
    const float* dw  = (const float*)d_in[7];
    const float* db  = (const float*)d_in[8];
    float* out = (float*)d_out;

    char* ws = (char*)d_ws;
    __bf16* A0  = (__bf16*)(ws + OFF_A0);
    __bf16* W0  = (__bf16*)(ws + OFF_W0);
    __bf16* A1  = (__bf16*)(ws + OFF_A1);
    float*  P0  = (float*)(ws + OFF_P0);
    __bf16* W1  = (__bf16*)(ws + OFF_W1);
    float*  P1  = (float*)(ws + OFF_P1);
    __bf16* h1r = (__bf16*)(ws + OFF_H1R);
    __bf16* dwb = (__bf16*)(ws + OFF_DW);

    // Layer 0: K = 9216, splitK=2 -> grid 16x16x2 = 512 blocks (2/CU)
    kan_wprep<<<(H0N * DIN) / 256, 256, 0, stream>>>(bw0, sw0, ss0, W0);
    kan_act<<<(BATCH * DIN) / 256, 256, 0, stream>>>(x, A0);
    gemm_big<<<dim3(H0N / 128, BATCH / 256, 2), 256, 0, stream>>>(
        A0, W0, P0, BATCH, H0N, DIN * 9, DIN * 9 / 2);

    // Layer 1: K = 18432, splitK=4 -> grid 8x16x4 = 512 blocks (2/CU)
    kan_wprep<<<(H1N * H0N) / 256, 256, 0, stream>>>(bw1, sw1, ss1, W1);
    kan_act_sum2<<<(BATCH * H0N) / 256, 256, 0, stream>>>(
        P0, P0 + (size_t)BATCH * H0N, A1);
    gemm_big<<<dim3(H1N / 128, BATCH / 256, 4), 256, 0, stream>>>(
        A1, W1, P1, BATCH, H1N, H0N * 9, H0N * 9 / 4);

    // relu(sum of 4 partials) -> bf16
    relu_sum4<<<(BATCH * H1N / 4) / 256, 256, 0, stream>>>(
        P1, (size_t)BATCH * H1N, h1r, BATCH * H1N / 4);

    // Dense: out = h1r @ dw^T + db  (K = 1024)
    f2bf<<<(LOUT * H1N) / 256, 256, 0, stream>>>(dw, dwb, LOUT * H1N);
    gemm_dense<<<dim3(LOUT / 128, BATCH / 128), 256, 0, stream>>>(
        h1r, dwb, out, db, BATCH, LOUT, H1N);
}